// Round 2
// baseline (368.322 us; speedup 1.0000x reference)
//
#include <hip/hip_runtime.h>
#include <hip/hip_bf16.h>
#include <math.h>

#define B 8
#define N 256
#define F 64
#define OUTD 256
typedef unsigned long long u64;

// ---------------------------------------------------------------------------
// pack: rowbits[b,i] bit k = (adj[b,i,k]!=0); colbits[b,i] bit k = (adj[b,k,i]!=0)
// grid: B blocks, 256 threads (4 waves)
// ---------------------------------------------------------------------------
__global__ void pack_kernel(const int* __restrict__ adj,
                            u64* __restrict__ rowbits,
                            u64* __restrict__ colbits) {
    int b = blockIdx.x;
    int t = threadIdx.x;
    int w = t >> 6;
    int lane = t & 63;
    __shared__ u64 rl[N][4];
    // phase 1: row masks via ballot (coalesced 256B reads per wave-op)
    for (int ii = 0; ii < 64; ++ii) {
        int i = w * 64 + ii;
        for (int wd = 0; wd < 4; ++wd) {
            int v = adj[(long)(b * N + i) * N + wd * 64 + lane];
            u64 bits = __ballot(v != 0);
            if (lane == 0) {
                rl[i][wd] = bits;
                rowbits[(b * N + i) * 4 + wd] = bits;
            }
        }
    }
    __syncthreads();
    // phase 2: col masks from row masks (transpose in LDS)
    int i = t;
    int iw = i >> 6, ib = i & 63;
    for (int wd = 0; wd < 4; ++wd) {
        u64 out = 0;
        for (int j = 0; j < 64; ++j)
            out |= ((rl[wd * 64 + j][iw] >> ib) & 1ull) << j;
        colbits[(b * N + i) * 4 + wd] = out;
    }
}

// ---------------------------------------------------------------------------
// prep: base[b,i,f] = sum_g Wnf[f,g] X[b,i,g];  P[b,i] = Wnm @ relu(base[b,i])
// grid: B*N blocks, 64 threads
// ---------------------------------------------------------------------------
__global__ void prep_kernel(const float* __restrict__ X,
                            const float* __restrict__ Wnf,
                            const float* __restrict__ Wnm,
                            float* __restrict__ base,
                            float* __restrict__ P) {
    int bi = blockIdx.x;
    int f = threadIdx.x;
    __shared__ float xs[F];
    __shared__ float rs[F];
    xs[f] = X[bi * F + f];
    __syncthreads();
    float acc = 0.f;
#pragma unroll
    for (int g = 0; g < F; ++g) acc += Wnf[f * F + g] * xs[g];
    base[bi * F + f] = acc;
    rs[f] = fmaxf(acc, 0.f);
    __syncthreads();
    float acc2 = 0.f;
#pragma unroll
    for (int g = 0; g < F; ++g) acc2 += Wnm[f * F + g] * rs[g];
    P[bi * F + f] = acc2;
}

// ---------------------------------------------------------------------------
// V2[b,i] = base[b,i] + sum_{k in both(i)} P[b,k]
// grid: (N,B), 64 threads
// ---------------------------------------------------------------------------
__global__ void v2_kernel(const float* __restrict__ base,
                          const float* __restrict__ P,
                          const u64* __restrict__ rowbits,
                          const u64* __restrict__ colbits,
                          float* __restrict__ V2) {
    int i = blockIdx.x, b = blockIdx.y;
    int f = threadIdx.x;
    int bi = b * N + i;
    float acc = base[bi * F + f];
    for (int wd = 0; wd < 4; ++wd) {
        u64 m = rowbits[bi * 4 + wd] & colbits[bi * 4 + wd];
        while (m) {
            int k = (wd << 6) + __builtin_ctzll(m);
            m &= m - 1;
            acc += P[(b * N + k) * F + f];
        }
    }
    V2[bi * F + f] = acc;
}

// ---------------------------------------------------------------------------
// S3 linearized: V3[b,i] = base[b,i] + Wnm @ (sum_{k in both(i)} relu(V2[b,k]-P[b,i]))
// grid: (N,B), 64 threads
// ---------------------------------------------------------------------------
__global__ void s3_kernel(const float* __restrict__ base,
                          const float* __restrict__ P,
                          const float* __restrict__ V2,
                          const u64* __restrict__ rowbits,
                          const u64* __restrict__ colbits,
                          const float* __restrict__ Wnm,
                          float* __restrict__ V3) {
    int i = blockIdx.x, b = blockIdx.y;
    int f = threadIdx.x;
    int bi = b * N + i;
    float pif = P[bi * F + f];
    float u = 0.f;
    for (int wd = 0; wd < 4; ++wd) {
        u64 m = rowbits[bi * 4 + wd] & colbits[bi * 4 + wd];
        while (m) {
            int k = (wd << 6) + __builtin_ctzll(m);
            m &= m - 1;
            u += fmaxf(V2[(b * N + k) * F + f] - pif, 0.f);
        }
    }
    float wrow[F];
#pragma unroll
    for (int g = 0; g < F; ++g) wrow[g] = Wnm[f * F + g];
    float a0 = 0.f, a1 = 0.f, a2 = 0.f, a3 = 0.f;
#pragma unroll
    for (int g = 0; g < F; g += 4) {
        a0 = fmaf(wrow[g + 0], __shfl(u, g + 0, 64), a0);
        a1 = fmaf(wrow[g + 1], __shfl(u, g + 1, 64), a1);
        a2 = fmaf(wrow[g + 2], __shfl(u, g + 2, 64), a2);
        a3 = fmaf(wrow[g + 3], __shfl(u, g + 3, 64), a3);
    }
    V3[bi * F + f] = base[bi * F + f] + ((a0 + a1) + (a2 + a3));
}

// ---------------------------------------------------------------------------
// bigstep (step4 + agg fused, T4 kept in LDS for this block's receiver i):
//   for k in both(i): T3ik = Wnm@relu(V2[i]-P[k]); T4ki = Wnm@relu(V3[k]-T3ik)
//                     S4 += T4ki; t4lds[k] = T4ki
//   V4 = base[i] + S4
//   agg[i] = sum_{j in both(i)} relu(V4 - t4lds[j]) + nsingle * relu(V4)
// grid: (N,B), 256 threads (4 waves split the k-space)
// ---------------------------------------------------------------------------
__global__ __launch_bounds__(256, 1) void bigstep_kernel(
        const float* __restrict__ base,
        const float* __restrict__ P,
        const float* __restrict__ V2,
        const float* __restrict__ V3,
        const u64* __restrict__ rowbits,
        const u64* __restrict__ colbits,
        const float* __restrict__ Wnm,
        float* __restrict__ agg) {
    int i = blockIdx.x, b = blockIdx.y;
    int t = threadIdx.x;
    int w = t >> 6, f = t & 63;
    int bi = b * N + i;
    __shared__ float t4lds[N][F];     // 64 KB
    __shared__ float red[4][F];
    u64 rm[4], bm[4];
    for (int wd = 0; wd < 4; ++wd) {
        u64 r = rowbits[bi * 4 + wd], c = colbits[bi * 4 + wd];
        rm[wd] = r;
        bm[wd] = r & c;
    }
    float wrow[F];
#pragma unroll
    for (int g = 0; g < F; ++g) wrow[g] = Wnm[f * F + g];
    float v2if = V2[bi * F + f];
    float s4 = 0.f;
    int c = 0;
    for (int wd = 0; wd < 4; ++wd) {
        u64 m = bm[wd];
        while (m) {
            int k = (wd << 6) + __builtin_ctzll(m);
            m &= m - 1;
            if ((c++ & 3) != w) continue;            // wave-uniform partition
            float m1 = fmaxf(v2if - P[(b * N + k) * F + f], 0.f);
            float a0 = 0.f, a1 = 0.f, a2 = 0.f, a3 = 0.f;
#pragma unroll
            for (int g = 0; g < F; g += 4) {
                a0 = fmaf(wrow[g + 0], __shfl(m1, g + 0, 64), a0);
                a1 = fmaf(wrow[g + 1], __shfl(m1, g + 1, 64), a1);
                a2 = fmaf(wrow[g + 2], __shfl(m1, g + 2, 64), a2);
                a3 = fmaf(wrow[g + 3], __shfl(m1, g + 3, 64), a3);
            }
            float t3ik = (a0 + a1) + (a2 + a3);
            float m2 = fmaxf(V3[(b * N + k) * F + f] - t3ik, 0.f);
            a0 = 0.f; a1 = 0.f; a2 = 0.f; a3 = 0.f;
#pragma unroll
            for (int g = 0; g < F; g += 4) {
                a0 = fmaf(wrow[g + 0], __shfl(m2, g + 0, 64), a0);
                a1 = fmaf(wrow[g + 1], __shfl(m2, g + 1, 64), a1);
                a2 = fmaf(wrow[g + 2], __shfl(m2, g + 2, 64), a2);
                a3 = fmaf(wrow[g + 3], __shfl(m2, g + 3, 64), a3);
            }
            float t4 = (a0 + a1) + (a2 + a3);
            s4 += t4;
            t4lds[k][f] = t4;
        }
    }
    red[w][f] = s4;
    __syncthreads();
    float v4 = base[bi * F + f] + ((red[0][f] + red[1][f]) + (red[2][f] + red[3][f]));
    float a = 0.f;
    c = 0;
    for (int wd = 0; wd < 4; ++wd) {
        u64 m = bm[wd];
        while (m) {
            int j = (wd << 6) + __builtin_ctzll(m);
            m &= m - 1;
            if ((c++ & 3) != w) continue;
            a += fmaxf(v4 - t4lds[j][f], 0.f);
        }
    }
    if (w == 0) {
        int ns = 0;
        for (int wd = 0; wd < 4; ++wd) ns += (int)__builtin_popcountll(rm[wd] & ~bm[wd]);
        a += (float)ns * fmaxf(v4, 0.f);
    }
    __syncthreads();                 // red reused below
    red[w][f] = a;
    __syncthreads();
    if (w == 0) agg[bi * F + f] = (red[0][f] + red[1][f]) + (red[2][f] + red[3][f]);
}

// ---------------------------------------------------------------------------
// encode: enc[b,n,f] = relu( sum_m Unf[n,m] X[b,m,f] + sum_g Unm[f,g] agg[b,n,g] )
// grid: (N,B), 64 threads
// ---------------------------------------------------------------------------
__global__ void encode_kernel(const float* __restrict__ X,
                              const float* __restrict__ Unf,
                              const float* __restrict__ Unm,
                              const float* __restrict__ agg,
                              float* __restrict__ enc) {
    int n = blockIdx.x, b = blockIdx.y;
    int f = threadIdx.x;
    __shared__ float as[F];
    as[f] = agg[(b * N + n) * F + f];
    __syncthreads();
    float acc = 0.f;
#pragma unroll
    for (int g = 0; g < F; ++g) acc += Unm[f * F + g] * as[g];
    const float* urow = Unf + n * N;
    for (int m = 0; m < N; ++m) acc += urow[m] * X[(b * N + m) * F + f];
    enc[(b * N + n) * F + f] = fmaxf(acc, 0.f);
}

// ---------------------------------------------------------------------------
// final: out[b,o] = sigmoid( sum_k enc_flat[b,k]*lw[o,k] + lb[o] )
// grid: OUTD blocks, 256 threads
// ---------------------------------------------------------------------------
__global__ void final_kernel(const float* __restrict__ enc,
                             const float* __restrict__ lw,
                             const float* __restrict__ lb,
                             float* __restrict__ out) {
    int o = blockIdx.x;
    int t = threadIdx.x;
    float acc[B];
#pragma unroll
    for (int b = 0; b < B; ++b) acc[b] = 0.f;
    const float* lrow = lw + (long)o * (N * F);
    for (int k = t; k < N * F; k += 256) {
        float wv = lrow[k];
#pragma unroll
        for (int b = 0; b < B; ++b) acc[b] += wv * enc[b * N * F + k];
    }
    __shared__ float red[B][256];
#pragma unroll
    for (int b = 0; b < B; ++b) red[b][t] = acc[b];
    __syncthreads();
    for (int off = 128; off > 0; off >>= 1) {
        if (t < off) {
#pragma unroll
            for (int b = 0; b < B; ++b) red[b][t] += red[b][t + off];
        }
        __syncthreads();
    }
    if (t < B) {
        float z = red[t][0] + lb[o];
        out[t * OUTD + o] = 1.f / (1.f + expf(-z));
    }
}

extern "C" void kernel_launch(void* const* d_in, const int* in_sizes, int n_in,
                              void* d_out, int out_size, void* d_ws, size_t ws_size,
                              hipStream_t stream) {
    const float* X   = (const float*)d_in[0];   // [B,N,F]
    const int*   adj = (const int*)d_in[1];     // [B,N,N]
    const float* Wnf = (const float*)d_in[2];   // [F,F]
    const float* Wnm = (const float*)d_in[3];   // [F,F]
    const float* Unf = (const float*)d_in[4];   // [N,N]
    const float* Unm = (const float*)d_in[5];   // [F,F]
    const float* lw  = (const float*)d_in[6];   // [OUTD, N*F]
    const float* lb  = (const float*)d_in[7];   // [OUTD]
    float* out = (float*)d_out;

    // workspace: 2*64KB bitmasks + 6 * 512KB float buffers = ~3.3 MB
    const long BNF = (long)B * N * F;           // 131072
    u64* rowbits = (u64*)d_ws;
    u64* colbits = rowbits + (long)B * N * 4;
    float* fws = (float*)(colbits + (long)B * N * 4);
    float* base = fws;          fws += BNF;
    float* P    = fws;          fws += BNF;
    float* V2   = fws;          fws += BNF;
    float* V3   = fws;          fws += BNF;
    float* aggp = fws;          fws += BNF;
    float* enc  = fws;          fws += BNF;
    (void)ws_size; (void)in_sizes; (void)n_in; (void)out_size;

    pack_kernel<<<B, 256, 0, stream>>>(adj, rowbits, colbits);
    prep_kernel<<<B * N, F, 0, stream>>>(X, Wnf, Wnm, base, P);
    v2_kernel<<<dim3(N, B), F, 0, stream>>>(base, P, rowbits, colbits, V2);
    s3_kernel<<<dim3(N, B), F, 0, stream>>>(base, P, V2, rowbits, colbits, Wnm, V3);
    bigstep_kernel<<<dim3(N, B), 256, 0, stream>>>(base, P, V2, V3, rowbits, colbits, Wnm, aggp);
    encode_kernel<<<dim3(N, B), F, 0, stream>>>(X, Unf, Unm, aggp, enc);
    final_kernel<<<OUTD, 256, 0, stream>>>(enc, lw, lb, out);
}

// Round 3
// 188.391 us; speedup vs baseline: 1.9551x; 1.9551x over previous
//
#include <hip/hip_runtime.h>
#include <hip/hip_bf16.h>
#include <math.h>

#define B 8
#define N 256
#define F 64
#define OUTD 256
typedef unsigned long long u64;
typedef __attribute__((ext_vector_type(8))) short bf16x8;
typedef __attribute__((ext_vector_type(4))) float f32x4;

// split x into hi+lo bf16 parts (truncation; residual <= 2^-16 |x|)
__device__ __forceinline__ void build_frag(const float* v8, bf16x8& h, bf16x8& l) {
#pragma unroll
    for (int j = 0; j < 8; ++j) {
        unsigned u = __float_as_uint(v8[j]);
        unsigned hb = u & 0xffff0000u;
        float r = v8[j] - __uint_as_float(hb);
        h[j] = (short)(hb >> 16);
        l[j] = (short)(__float_as_uint(r) >> 16);
    }
}

// ---------------------------------------------------------------------------
// pack: rowbits[b,i] bit k = adj[b,i,k]!=0 ; colbits[b,i] bit k = adj[b,k,i]!=0
// ---------------------------------------------------------------------------
__global__ __launch_bounds__(256) void pack_kernel(const int* __restrict__ adj,
                                                   u64* __restrict__ rowbits,
                                                   u64* __restrict__ colbits) {
    int b = blockIdx.x;
    int t = threadIdx.x;
    int w = t >> 6;
    int lane = t & 63;
    __shared__ u64 rl[N][4];
    for (int ii = 0; ii < 64; ++ii) {
        int i = w * 64 + ii;
        for (int wd = 0; wd < 4; ++wd) {
            int v = adj[(long)(b * N + i) * N + wd * 64 + lane];
            u64 bits = __ballot(v != 0);
            if (lane == 0) {
                rl[i][wd] = bits;
                rowbits[(b * N + i) * 4 + wd] = bits;
            }
        }
    }
    __syncthreads();
    int i = t;
    int iw = i >> 6, ib = i & 63;
    for (int wd = 0; wd < 4; ++wd) {
        u64 out = 0;
        for (int j = 0; j < 64; ++j)
            out |= ((rl[wd * 64 + j][iw] >> ib) & 1ull) << j;
        colbits[(b * N + i) * 4 + wd] = out;
    }
}

// ---------------------------------------------------------------------------
// prep: base = Wnf@x ; P = Wnm@relu(base)
// ---------------------------------------------------------------------------
__global__ __launch_bounds__(64) void prep_kernel(const float* __restrict__ X,
                                                  const float* __restrict__ Wnf,
                                                  const float* __restrict__ Wnm,
                                                  float* __restrict__ base,
                                                  float* __restrict__ P) {
    int bi = blockIdx.x;
    int f = threadIdx.x;
    __shared__ float xs[F];
    __shared__ float rs[F];
    xs[f] = X[bi * F + f];
    __syncthreads();
    float acc = 0.f;
#pragma unroll
    for (int g = 0; g < F; ++g) acc += Wnf[f * F + g] * xs[g];
    base[bi * F + f] = acc;
    rs[f] = fmaxf(acc, 0.f);
    __syncthreads();
    float acc2 = 0.f;
#pragma unroll
    for (int g = 0; g < F; ++g) acc2 += Wnm[f * F + g] * rs[g];
    P[bi * F + f] = acc2;
}

// ---------------------------------------------------------------------------
// V2[b,i] = base[b,i] + sum_{k in both(i)} P[b,k]   (4 waves split k)
// ---------------------------------------------------------------------------
__global__ __launch_bounds__(256) void v2_kernel(const float* __restrict__ base,
                                                 const float* __restrict__ P,
                                                 const u64* __restrict__ rowbits,
                                                 const u64* __restrict__ colbits,
                                                 float* __restrict__ V2) {
    int i = blockIdx.x, b = blockIdx.y;
    int t = threadIdx.x, w = t >> 6, f = t & 63;
    int bi = b * N + i;
    __shared__ float red[4][F];
    u64 both = rowbits[bi * 4 + w] & colbits[bi * 4 + w];
    const float* Pb = P + (size_t)b * N * F;
    float acc = 0.f;
    for (int j = 0; j < 64; ++j) {
        float mk = ((both >> j) & 1ull) ? 1.f : 0.f;
        acc += mk * Pb[(w * 64 + j) * F + f];
    }
    red[w][f] = acc;
    __syncthreads();
    if (t < F) V2[bi * F + t] = base[bi * F + t] + red[0][t] + red[1][t] + red[2][t] + red[3][t];
}

// ---------------------------------------------------------------------------
// V3[b,i] = base[b,i] + Wnm @ (sum_{k in both(i)} relu(V2[b,k]-P[b,i]))
// ---------------------------------------------------------------------------
__global__ __launch_bounds__(256) void s3_kernel(const float* __restrict__ base,
                                                 const float* __restrict__ P,
                                                 const float* __restrict__ V2g,
                                                 const u64* __restrict__ rowbits,
                                                 const u64* __restrict__ colbits,
                                                 const float* __restrict__ Wnm,
                                                 float* __restrict__ V3) {
    int i = blockIdx.x, b = blockIdx.y;
    int t = threadIdx.x, w = t >> 6, f = t & 63;
    int bi = b * N + i;
    __shared__ float red[4][F];
    __shared__ float ubuf[F];
    u64 both = rowbits[bi * 4 + w] & colbits[bi * 4 + w];
    float pif = P[(size_t)bi * F + f];
    const float* Vb = V2g + (size_t)b * N * F;
    float acc = 0.f;
    for (int j = 0; j < 64; ++j) {
        float mk = ((both >> j) & 1ull) ? 1.f : 0.f;
        acc += mk * fmaxf(Vb[(w * 64 + j) * F + f] - pif, 0.f);
    }
    red[w][f] = acc;
    __syncthreads();
    if (t < F) ubuf[t] = red[0][t] + red[1][t] + red[2][t] + red[3][t];
    __syncthreads();
    if (w == 0) {
        float u = ubuf[f];
        float wrow[F];
        const float4* wr = (const float4*)(Wnm + (size_t)f * F);
#pragma unroll
        for (int q = 0; q < 16; ++q) *(float4*)&wrow[q * 4] = wr[q];
        float a = 0.f;
#pragma unroll
        for (int g = 0; g < F; ++g) a = fmaf(wrow[g], __shfl(u, g, 64), a);
        V3[bi * F + f] = base[bi * F + f] + a;
    }
}

// ---------------------------------------------------------------------------
// bigstep via MFMA (hi/lo bf16 3-pass ~ fp32):
//   per receiver i (block), 4 waves each own a 64-wide sender chunk:
//   GEMM1: T3[g][k] = Wnm @ relu(V2[i] - P[k])      (B-frags from global)
//   M2[g][k] = both(k) ? relu(V3[k][g] - T3[g][k]) : 0    (via LDS f32)
//   GEMM2: T4[f][k] = Wnm @ M2
//   S4 = sum_k T4 ; V4 = base[i] + S4
//   agg[i][f] = sum_{k in row(i)} relu(V4[f] - T4[f][k])   (T4 col=0 for row-only k)
// ---------------------------------------------------------------------------
__global__ __launch_bounds__(256, 1) void bigstep_kernel(
        const float* __restrict__ base,
        const float* __restrict__ P,
        const float* __restrict__ V2g,
        const float* __restrict__ V3,
        const u64* __restrict__ rowbits,
        const u64* __restrict__ colbits,
        const float* __restrict__ Wnm,
        float* __restrict__ agg) {
    int i = blockIdx.x, b = blockIdx.y;
    int t = threadIdx.x;
    int w = t >> 6, l = t & 63;
    int ln = l & 15, grp = l >> 4;
    int bi = b * N + i;
    int bN = b * N;
    __shared__ float m2lds[4][64][68];   // per-wave [k_local][g] f32, padded
    __shared__ float red[4][F];
    __shared__ float v4buf[F];

    u64 rw = rowbits[bi * 4 + w];
    u64 cw = colbits[bi * 4 + w];
    u64 bothw = rw & cw;

    // A fragments: Wnm[m][g], m = 16ft+ln, g = 32ks+8grp+j  (hi/lo)
    bf16x8 Ah[8], Al[8];
#pragma unroll
    for (int ft = 0; ft < 4; ++ft) {
        const float4* wr = (const float4*)(Wnm + (size_t)(16 * ft + ln) * F);
#pragma unroll
        for (int ks = 0; ks < 2; ++ks) {
            float e[8];
            *(float4*)&e[0] = wr[8 * ks + 2 * grp];
            *(float4*)&e[4] = wr[8 * ks + 2 * grp + 1];
            build_frag(e, Ah[ft * 2 + ks], Al[ft * 2 + ks]);
        }
    }
    // V2[i] at this lane's g positions
    float v2f[2][8];
    {
        const float4* vr = (const float4*)(V2g + (size_t)bi * F);
#pragma unroll
        for (int ks = 0; ks < 2; ++ks) {
            *(float4*)&v2f[ks][0] = vr[8 * ks + 2 * grp];
            *(float4*)&v2f[ks][4] = vr[8 * ks + 2 * grp + 1];
        }
    }

    // ---- GEMM1 ----
    f32x4 acc1[4][4];
#pragma unroll
    for (int ft = 0; ft < 4; ++ft)
#pragma unroll
        for (int kt = 0; kt < 4; ++kt) acc1[ft][kt] = (f32x4){0.f, 0.f, 0.f, 0.f};

#pragma unroll
    for (int kt = 0; kt < 4; ++kt) {
        int kglob = w * 64 + kt * 16 + ln;
        const float4* pr = (const float4*)(P + (size_t)(bN + kglob) * F);
#pragma unroll
        for (int ks = 0; ks < 2; ++ks) {
            float e[8];
            *(float4*)&e[0] = pr[8 * ks + 2 * grp];
            *(float4*)&e[4] = pr[8 * ks + 2 * grp + 1];
#pragma unroll
            for (int j = 0; j < 8; ++j) e[j] = fmaxf(v2f[ks][j] - e[j], 0.f);
            bf16x8 Bh, Bl;
            build_frag(e, Bh, Bl);
#pragma unroll
            for (int ft = 0; ft < 4; ++ft) {
                acc1[ft][kt] = __builtin_amdgcn_mfma_f32_16x16x32_bf16(Ah[ft * 2 + ks], Bh, acc1[ft][kt], 0, 0, 0);
                acc1[ft][kt] = __builtin_amdgcn_mfma_f32_16x16x32_bf16(Ah[ft * 2 + ks], Bl, acc1[ft][kt], 0, 0, 0);
                acc1[ft][kt] = __builtin_amdgcn_mfma_f32_16x16x32_bf16(Al[ft * 2 + ks], Bh, acc1[ft][kt], 0, 0, 0);
            }
        }
    }

    // ---- M2 build into LDS (f32) ----
#pragma unroll
    for (int kt = 0; kt < 4; ++kt) {
        int kloc = kt * 16 + ln;
        int kglob = w * 64 + kloc;
        float km = ((bothw >> kloc) & 1ull) ? 1.f : 0.f;
        const float* v3r = V3 + (size_t)(bN + kglob) * F;
#pragma unroll
        for (int ft = 0; ft < 4; ++ft) {
            int g0 = 16 * ft + 4 * grp;
            float4 v3v = *(const float4*)(v3r + g0);
            f32x4 tq = acc1[ft][kt];
            float4 m2v;
            m2v.x = km * fmaxf(v3v.x - tq[0], 0.f);
            m2v.y = km * fmaxf(v3v.y - tq[1], 0.f);
            m2v.z = km * fmaxf(v3v.z - tq[2], 0.f);
            m2v.w = km * fmaxf(v3v.w - tq[3], 0.f);
            *(float4*)&m2lds[w][kloc][g0] = m2v;
        }
    }

    // ---- GEMM2 ----
    f32x4 acc2[4][4];
#pragma unroll
    for (int ft = 0; ft < 4; ++ft)
#pragma unroll
        for (int kt = 0; kt < 4; ++kt) acc2[ft][kt] = (f32x4){0.f, 0.f, 0.f, 0.f};

#pragma unroll
    for (int kt = 0; kt < 4; ++kt) {
        int kloc = kt * 16 + ln;
#pragma unroll
        for (int ks = 0; ks < 2; ++ks) {
            int g0 = 32 * ks + 8 * grp;
            float e[8];
            *(float4*)&e[0] = *(const float4*)&m2lds[w][kloc][g0];
            *(float4*)&e[4] = *(const float4*)&m2lds[w][kloc][g0 + 4];
            bf16x8 Bh, Bl;
            build_frag(e, Bh, Bl);
#pragma unroll
            for (int ft = 0; ft < 4; ++ft) {
                acc2[ft][kt] = __builtin_amdgcn_mfma_f32_16x16x32_bf16(Ah[ft * 2 + ks], Bh, acc2[ft][kt], 0, 0, 0);
                acc2[ft][kt] = __builtin_amdgcn_mfma_f32_16x16x32_bf16(Ah[ft * 2 + ks], Bl, acc2[ft][kt], 0, 0, 0);
                acc2[ft][kt] = __builtin_amdgcn_mfma_f32_16x16x32_bf16(Al[ft * 2 + ks], Bh, acc2[ft][kt], 0, 0, 0);
            }
        }
    }

    // ---- S4 reduce ----
    float s4[4][4];
#pragma unroll
    for (int ft = 0; ft < 4; ++ft)
#pragma unroll
        for (int r = 0; r < 4; ++r)
            s4[ft][r] = acc2[ft][0][r] + acc2[ft][1][r] + acc2[ft][2][r] + acc2[ft][3][r];
#pragma unroll
    for (int m = 1; m <= 8; m <<= 1)
#pragma unroll
        for (int ft = 0; ft < 4; ++ft)
#pragma unroll
            for (int r = 0; r < 4; ++r)
                s4[ft][r] += __shfl_xor(s4[ft][r], m, 64);
    if (ln == 0) {
#pragma unroll
        for (int ft = 0; ft < 4; ++ft) {
            float4 q = make_float4(s4[ft][0], s4[ft][1], s4[ft][2], s4[ft][3]);
            *(float4*)&red[w][16 * ft + 4 * grp] = q;
        }
    }
    __syncthreads();
    if (t < F) v4buf[t] = base[(size_t)bi * F + t] + red[0][t] + red[1][t] + red[2][t] + red[3][t];
    __syncthreads();

    // ---- agg ----
    float v4r[4][4];
#pragma unroll
    for (int ft = 0; ft < 4; ++ft) {
        float4 q = *(const float4*)&v4buf[16 * ft + 4 * grp];
        v4r[ft][0] = q.x; v4r[ft][1] = q.y; v4r[ft][2] = q.z; v4r[ft][3] = q.w;
    }
    float av[4][4];
#pragma unroll
    for (int ft = 0; ft < 4; ++ft)
#pragma unroll
        for (int r = 0; r < 4; ++r) av[ft][r] = 0.f;
#pragma unroll
    for (int kt = 0; kt < 4; ++kt) {
        float rbm = ((rw >> (kt * 16 + ln)) & 1ull) ? 1.f : 0.f;
#pragma unroll
        for (int ft = 0; ft < 4; ++ft)
#pragma unroll
            for (int r = 0; r < 4; ++r)
                av[ft][r] += rbm * fmaxf(v4r[ft][r] - acc2[ft][kt][r], 0.f);
    }
#pragma unroll
    for (int m = 1; m <= 8; m <<= 1)
#pragma unroll
        for (int ft = 0; ft < 4; ++ft)
#pragma unroll
            for (int r = 0; r < 4; ++r)
                av[ft][r] += __shfl_xor(av[ft][r], m, 64);
    if (ln == 0) {
#pragma unroll
        for (int ft = 0; ft < 4; ++ft) {
            float4 q = make_float4(av[ft][0], av[ft][1], av[ft][2], av[ft][3]);
            *(float4*)&red[w][16 * ft + 4 * grp] = q;
        }
    }
    __syncthreads();
    if (t < F) agg[(size_t)bi * F + t] = red[0][t] + red[1][t] + red[2][t] + red[3][t];
}

// ---------------------------------------------------------------------------
// encode: enc = relu(Unf@X + Unm@agg)   (4 waves split m)
// ---------------------------------------------------------------------------
__global__ __launch_bounds__(256) void encode_kernel(const float* __restrict__ X,
                                                     const float* __restrict__ Unf,
                                                     const float* __restrict__ Unm,
                                                     const float* __restrict__ agg,
                                                     float* __restrict__ enc) {
    int n = blockIdx.x, b = blockIdx.y;
    int t = threadIdx.x, w = t >> 6, f = t & 63;
    __shared__ float red[4][F];
    const float* urow = Unf + (size_t)n * N;
    const float* Xb = X + (size_t)b * N * F;
    float acc = 0.f;
    for (int j = 0; j < 64; ++j) {
        int m = w * 64 + j;
        acc += urow[m] * Xb[m * F + f];
    }
    red[w][f] = acc;
    __syncthreads();
    if (w == 0) {
        float msum = red[0][f] + red[1][f] + red[2][f] + red[3][f];
        float ag = agg[((size_t)b * N + n) * F + f];
        float wrow[F];
        const float4* wr = (const float4*)(Unm + (size_t)f * F);
#pragma unroll
        for (int q = 0; q < 16; ++q) *(float4*)&wrow[q * 4] = wr[q];
        float a = 0.f;
#pragma unroll
        for (int g = 0; g < F; ++g) a = fmaf(wrow[g], __shfl(ag, g, 64), a);
        enc[((size_t)b * N + n) * F + f] = fmaxf(msum + a, 0.f);
    }
}

// ---------------------------------------------------------------------------
// final: out[b,o] = sigmoid(enc_flat[b] . lw[o] + lb[o])   (float4 loads)
// ---------------------------------------------------------------------------
__global__ __launch_bounds__(256) void final_kernel(const float* __restrict__ enc,
                                                    const float* __restrict__ lw,
                                                    const float* __restrict__ lb,
                                                    float* __restrict__ out) {
    int o = blockIdx.x;
    int t = threadIdx.x;
    float acc[B];
#pragma unroll
    for (int b = 0; b < B; ++b) acc[b] = 0.f;
    const float4* lrow = (const float4*)(lw + (size_t)o * (N * F));
    const float4* e4 = (const float4*)enc;
    for (int k = t; k < (N * F) / 4; k += 256) {
        float4 wv = lrow[k];
#pragma unroll
        for (int b = 0; b < B; ++b) {
            float4 ev = e4[b * (N * F / 4) + k];
            acc[b] += wv.x * ev.x + wv.y * ev.y + wv.z * ev.z + wv.w * ev.w;
        }
    }
    __shared__ float red[B][256];
#pragma unroll
    for (int b = 0; b < B; ++b) red[b][t] = acc[b];
    __syncthreads();
    for (int off = 128; off > 0; off >>= 1) {
        if (t < off) {
#pragma unroll
            for (int b = 0; b < B; ++b) red[b][t] += red[b][t + off];
        }
        __syncthreads();
    }
    if (t < B) {
        float z = red[t][0] + lb[o];
        out[t * OUTD + o] = 1.f / (1.f + expf(-z));
    }
}

extern "C" void kernel_launch(void* const* d_in, const int* in_sizes, int n_in,
                              void* d_out, int out_size, void* d_ws, size_t ws_size,
                              hipStream_t stream) {
    const float* X   = (const float*)d_in[0];
    const int*   adj = (const int*)d_in[1];
    const float* Wnf = (const float*)d_in[2];
    const float* Wnm = (const float*)d_in[3];
    const float* Unf = (const float*)d_in[4];
    const float* Unm = (const float*)d_in[5];
    const float* lw  = (const float*)d_in[6];
    const float* lb  = (const float*)d_in[7];
    float* out = (float*)d_out;

    const long BNF = (long)B * N * F;
    u64* rowbits = (u64*)d_ws;
    u64* colbits = rowbits + (long)B * N * 4;
    float* fws = (float*)(colbits + (long)B * N * 4);
    float* base = fws;          fws += BNF;
    float* P    = fws;          fws += BNF;
    float* V2   = fws;          fws += BNF;
    float* V3   = fws;          fws += BNF;
    float* aggp = fws;          fws += BNF;
    float* enc  = fws;          fws += BNF;
    (void)ws_size; (void)in_sizes; (void)n_in; (void)out_size;

    pack_kernel<<<B, 256, 0, stream>>>(adj, rowbits, colbits);
    prep_kernel<<<B * N, F, 0, stream>>>(X, Wnf, Wnm, base, P);
    v2_kernel<<<dim3(N, B), 256, 0, stream>>>(base, P, rowbits, colbits, V2);
    s3_kernel<<<dim3(N, B), 256, 0, stream>>>(base, P, V2, rowbits, colbits, Wnm, V3);
    bigstep_kernel<<<dim3(N, B), 256, 0, stream>>>(base, P, V2, V3, rowbits, colbits, Wnm, aggp);
    encode_kernel<<<dim3(N, B), 256, 0, stream>>>(X, Unf, Unm, aggp, enc);
    final_kernel<<<OUTD, 256, 0, stream>>>(enc, lw, lb, out);
}

// Round 4
// 121.628 us; speedup vs baseline: 3.0283x; 1.5489x over previous
//
#include <hip/hip_runtime.h>
#include <hip/hip_bf16.h>
#include <math.h>

#define B 8
#define N 256
#define F 64
#define OUTD 256
typedef unsigned long long u64;
typedef __attribute__((ext_vector_type(8))) short bf16x8;
typedef __attribute__((ext_vector_type(4))) float f32x4;

// split x into hi+lo bf16 parts (truncation; residual <= 2^-16 |x|)
__device__ __forceinline__ void build_frag(const float* v8, bf16x8& h, bf16x8& l) {
#pragma unroll
    for (int j = 0; j < 8; ++j) {
        unsigned u = __float_as_uint(v8[j]);
        unsigned hb = u & 0xffff0000u;
        float r = v8[j] - __uint_as_float(hb);
        h[j] = (short)(hb >> 16);
        l[j] = (short)(__float_as_uint(r) >> 16);
    }
}

// ---------------------------------------------------------------------------
// pack_rows: rowbits[b,i] bit k = adj[b,i,k]!=0
// grid (N/4, B), 256 threads: wave w handles row i = bx*4+w
// ---------------------------------------------------------------------------
__global__ __launch_bounds__(256) void pack_rows_kernel(const int* __restrict__ adj,
                                                        u64* __restrict__ rowbits) {
    int b = blockIdx.y;
    int i = blockIdx.x * 4 + (threadIdx.x >> 6);
    int lane = threadIdx.x & 63;
#pragma unroll
    for (int wd = 0; wd < 4; ++wd) {
        int v = adj[(long)(b * N + i) * N + wd * 64 + lane];
        u64 bits = __ballot(v != 0);
        if (lane == 0) rowbits[(b * N + i) * 4 + wd] = bits;
    }
}

// ---------------------------------------------------------------------------
// pack_cols: colbits[b,i] bit k = adj[b,k,i]!=0 = rowbits[b,k] bit i
// grid (N/4, B), 256 threads: wave w handles node i = bx*4+w; lane j scans k=wd*64+j
// ---------------------------------------------------------------------------
__global__ __launch_bounds__(256) void pack_cols_kernel(const u64* __restrict__ rowbits,
                                                        u64* __restrict__ colbits) {
    int b = blockIdx.y;
    int i = blockIdx.x * 4 + (threadIdx.x >> 6);
    int lane = threadIdx.x & 63;
    int iw = i >> 6, ib = i & 63;
#pragma unroll
    for (int wd = 0; wd < 4; ++wd) {
        u64 rv = rowbits[(b * N + wd * 64 + lane) * 4 + iw];
        u64 bits = __ballot((rv >> ib) & 1ull);
        if (lane == 0) colbits[(b * N + i) * 4 + wd] = bits;
    }
}

// ---------------------------------------------------------------------------
// prep: base = Wnf@x ; P = Wnm@relu(base)
// ---------------------------------------------------------------------------
__global__ __launch_bounds__(64) void prep_kernel(const float* __restrict__ X,
                                                  const float* __restrict__ Wnf,
                                                  const float* __restrict__ Wnm,
                                                  float* __restrict__ base,
                                                  float* __restrict__ P) {
    int bi = blockIdx.x;
    int f = threadIdx.x;
    __shared__ float xs[F];
    __shared__ float rs[F];
    xs[f] = X[bi * F + f];
    __syncthreads();
    float acc = 0.f;
#pragma unroll
    for (int g = 0; g < F; ++g) acc += Wnf[f * F + g] * xs[g];
    base[bi * F + f] = acc;
    rs[f] = fmaxf(acc, 0.f);
    __syncthreads();
    float acc2 = 0.f;
#pragma unroll
    for (int g = 0; g < F; ++g) acc2 += Wnm[f * F + g] * rs[g];
    P[bi * F + f] = acc2;
}

// ---------------------------------------------------------------------------
// V2[b,i] = base[b,i] + sum_{k in both(i)} P[b,k]   (4 waves split k)
// ---------------------------------------------------------------------------
__global__ __launch_bounds__(256) void v2_kernel(const float* __restrict__ base,
                                                 const float* __restrict__ P,
                                                 const u64* __restrict__ rowbits,
                                                 const u64* __restrict__ colbits,
                                                 float* __restrict__ V2) {
    int i = blockIdx.x, b = blockIdx.y;
    int t = threadIdx.x, w = t >> 6, f = t & 63;
    int bi = b * N + i;
    __shared__ float red[4][F];
    u64 both = rowbits[bi * 4 + w] & colbits[bi * 4 + w];
    const float* Pb = P + (size_t)b * N * F;
    float acc = 0.f;
    for (int j = 0; j < 64; ++j) {
        float mk = ((both >> j) & 1ull) ? 1.f : 0.f;
        acc += mk * Pb[(w * 64 + j) * F + f];
    }
    red[w][f] = acc;
    __syncthreads();
    if (t < F) V2[bi * F + t] = base[bi * F + t] + red[0][t] + red[1][t] + red[2][t] + red[3][t];
}

// ---------------------------------------------------------------------------
// V3[b,i] = base[b,i] + Wnm @ (sum_{k in both(i)} relu(V2[b,k]-P[b,i]))
// ---------------------------------------------------------------------------
__global__ __launch_bounds__(256) void s3_kernel(const float* __restrict__ base,
                                                 const float* __restrict__ P,
                                                 const float* __restrict__ V2g,
                                                 const u64* __restrict__ rowbits,
                                                 const u64* __restrict__ colbits,
                                                 const float* __restrict__ Wnm,
                                                 float* __restrict__ V3) {
    int i = blockIdx.x, b = blockIdx.y;
    int t = threadIdx.x, w = t >> 6, f = t & 63;
    int bi = b * N + i;
    __shared__ float red[4][F];
    __shared__ float ubuf[F];
    u64 both = rowbits[bi * 4 + w] & colbits[bi * 4 + w];
    float pif = P[(size_t)bi * F + f];
    const float* Vb = V2g + (size_t)b * N * F;
    float acc = 0.f;
    for (int j = 0; j < 64; ++j) {
        float mk = ((both >> j) & 1ull) ? 1.f : 0.f;
        acc += mk * fmaxf(Vb[(w * 64 + j) * F + f] - pif, 0.f);
    }
    red[w][f] = acc;
    __syncthreads();
    if (t < F) ubuf[t] = red[0][t] + red[1][t] + red[2][t] + red[3][t];
    __syncthreads();
    if (w == 0) {
        float u = ubuf[f];
        float wrow[F];
        const float4* wr = (const float4*)(Wnm + (size_t)f * F);
#pragma unroll
        for (int q = 0; q < 16; ++q) *(float4*)&wrow[q * 4] = wr[q];
        float a = 0.f;
#pragma unroll
        for (int g = 0; g < F; ++g) a = fmaf(wrow[g], __shfl(u, g, 64), a);
        V3[bi * F + f] = base[bi * F + f] + a;
    }
}

// ---------------------------------------------------------------------------
// bigstep via MFMA (hi/lo bf16 3-pass ~ fp32):
//   per receiver i (block), 4 waves each own a 64-wide sender chunk:
//   GEMM1: T3[g][k] = Wnm @ relu(V2[i] - P[k])      (B-frags from global)
//   M2[g][k] = both(k) ? relu(V3[k][g] - T3[g][k]) : 0    (via LDS f32)
//   GEMM2: T4[f][k] = Wnm @ M2
//   S4 = sum_k T4 ; V4 = base[i] + S4
//   agg[i][f] = sum_{k in row(i)} relu(V4[f] - T4[f][k])   (T4 col=0 for row-only k)
// ---------------------------------------------------------------------------
__global__ __launch_bounds__(256, 1) void bigstep_kernel(
        const float* __restrict__ base,
        const float* __restrict__ P,
        const float* __restrict__ V2g,
        const float* __restrict__ V3,
        const u64* __restrict__ rowbits,
        const u64* __restrict__ colbits,
        const float* __restrict__ Wnm,
        float* __restrict__ agg) {
    int i = blockIdx.x, b = blockIdx.y;
    int t = threadIdx.x;
    int w = t >> 6, l = t & 63;
    int ln = l & 15, grp = l >> 4;
    int bi = b * N + i;
    int bN = b * N;
    __shared__ float m2lds[4][64][68];   // per-wave [k_local][g] f32, padded
    __shared__ float red[4][F];
    __shared__ float v4buf[F];

    u64 rw = rowbits[bi * 4 + w];
    u64 cw = colbits[bi * 4 + w];
    u64 bothw = rw & cw;

    // A fragments: Wnm[m][g], m = 16ft+ln, g = 32ks+8grp+j  (hi/lo)
    bf16x8 Ah[8], Al[8];
#pragma unroll
    for (int ft = 0; ft < 4; ++ft) {
        const float4* wr = (const float4*)(Wnm + (size_t)(16 * ft + ln) * F);
#pragma unroll
        for (int ks = 0; ks < 2; ++ks) {
            float e[8];
            *(float4*)&e[0] = wr[8 * ks + 2 * grp];
            *(float4*)&e[4] = wr[8 * ks + 2 * grp + 1];
            build_frag(e, Ah[ft * 2 + ks], Al[ft * 2 + ks]);
        }
    }
    // V2[i] at this lane's g positions
    float v2f[2][8];
    {
        const float4* vr = (const float4*)(V2g + (size_t)bi * F);
#pragma unroll
        for (int ks = 0; ks < 2; ++ks) {
            *(float4*)&v2f[ks][0] = vr[8 * ks + 2 * grp];
            *(float4*)&v2f[ks][4] = vr[8 * ks + 2 * grp + 1];
        }
    }

    // ---- GEMM1 ----
    f32x4 acc1[4][4];
#pragma unroll
    for (int ft = 0; ft < 4; ++ft)
#pragma unroll
        for (int kt = 0; kt < 4; ++kt) acc1[ft][kt] = (f32x4){0.f, 0.f, 0.f, 0.f};

#pragma unroll
    for (int kt = 0; kt < 4; ++kt) {
        int kglob = w * 64 + kt * 16 + ln;
        const float4* pr = (const float4*)(P + (size_t)(bN + kglob) * F);
#pragma unroll
        for (int ks = 0; ks < 2; ++ks) {
            float e[8];
            *(float4*)&e[0] = pr[8 * ks + 2 * grp];
            *(float4*)&e[4] = pr[8 * ks + 2 * grp + 1];
#pragma unroll
            for (int j = 0; j < 8; ++j) e[j] = fmaxf(v2f[ks][j] - e[j], 0.f);
            bf16x8 Bh, Bl;
            build_frag(e, Bh, Bl);
#pragma unroll
            for (int ft = 0; ft < 4; ++ft) {
                acc1[ft][kt] = __builtin_amdgcn_mfma_f32_16x16x32_bf16(Ah[ft * 2 + ks], Bh, acc1[ft][kt], 0, 0, 0);
                acc1[ft][kt] = __builtin_amdgcn_mfma_f32_16x16x32_bf16(Ah[ft * 2 + ks], Bl, acc1[ft][kt], 0, 0, 0);
                acc1[ft][kt] = __builtin_amdgcn_mfma_f32_16x16x32_bf16(Al[ft * 2 + ks], Bh, acc1[ft][kt], 0, 0, 0);
            }
        }
    }

    // ---- M2 build into LDS (f32) ----
#pragma unroll
    for (int kt = 0; kt < 4; ++kt) {
        int kloc = kt * 16 + ln;
        int kglob = w * 64 + kloc;
        float km = ((bothw >> kloc) & 1ull) ? 1.f : 0.f;
        const float* v3r = V3 + (size_t)(bN + kglob) * F;
#pragma unroll
        for (int ft = 0; ft < 4; ++ft) {
            int g0 = 16 * ft + 4 * grp;
            float4 v3v = *(const float4*)(v3r + g0);
            f32x4 tq = acc1[ft][kt];
            float4 m2v;
            m2v.x = km * fmaxf(v3v.x - tq[0], 0.f);
            m2v.y = km * fmaxf(v3v.y - tq[1], 0.f);
            m2v.z = km * fmaxf(v3v.z - tq[2], 0.f);
            m2v.w = km * fmaxf(v3v.w - tq[3], 0.f);
            *(float4*)&m2lds[w][kloc][g0] = m2v;
        }
    }

    // ---- GEMM2 ----
    f32x4 acc2[4][4];
#pragma unroll
    for (int ft = 0; ft < 4; ++ft)
#pragma unroll
        for (int kt = 0; kt < 4; ++kt) acc2[ft][kt] = (f32x4){0.f, 0.f, 0.f, 0.f};

#pragma unroll
    for (int kt = 0; kt < 4; ++kt) {
        int kloc = kt * 16 + ln;
#pragma unroll
        for (int ks = 0; ks < 2; ++ks) {
            int g0 = 32 * ks + 8 * grp;
            float e[8];
            *(float4*)&e[0] = *(const float4*)&m2lds[w][kloc][g0];
            *(float4*)&e[4] = *(const float4*)&m2lds[w][kloc][g0 + 4];
            bf16x8 Bh, Bl;
            build_frag(e, Bh, Bl);
#pragma unroll
            for (int ft = 0; ft < 4; ++ft) {
                acc2[ft][kt] = __builtin_amdgcn_mfma_f32_16x16x32_bf16(Ah[ft * 2 + ks], Bh, acc2[ft][kt], 0, 0, 0);
                acc2[ft][kt] = __builtin_amdgcn_mfma_f32_16x16x32_bf16(Ah[ft * 2 + ks], Bl, acc2[ft][kt], 0, 0, 0);
                acc2[ft][kt] = __builtin_amdgcn_mfma_f32_16x16x32_bf16(Al[ft * 2 + ks], Bh, acc2[ft][kt], 0, 0, 0);
            }
        }
    }

    // ---- S4 reduce ----
    float s4[4][4];
#pragma unroll
    for (int ft = 0; ft < 4; ++ft)
#pragma unroll
        for (int r = 0; r < 4; ++r)
            s4[ft][r] = acc2[ft][0][r] + acc2[ft][1][r] + acc2[ft][2][r] + acc2[ft][3][r];
#pragma unroll
    for (int m = 1; m <= 8; m <<= 1)
#pragma unroll
        for (int ft = 0; ft < 4; ++ft)
#pragma unroll
            for (int r = 0; r < 4; ++r)
                s4[ft][r] += __shfl_xor(s4[ft][r], m, 64);
    if (ln == 0) {
#pragma unroll
        for (int ft = 0; ft < 4; ++ft) {
            float4 q = make_float4(s4[ft][0], s4[ft][1], s4[ft][2], s4[ft][3]);
            *(float4*)&red[w][16 * ft + 4 * grp] = q;
        }
    }
    __syncthreads();
    if (t < F) v4buf[t] = base[(size_t)bi * F + t] + red[0][t] + red[1][t] + red[2][t] + red[3][t];
    __syncthreads();

    // ---- agg ----
    float v4r[4][4];
#pragma unroll
    for (int ft = 0; ft < 4; ++ft) {
        float4 q = *(const float4*)&v4buf[16 * ft + 4 * grp];
        v4r[ft][0] = q.x; v4r[ft][1] = q.y; v4r[ft][2] = q.z; v4r[ft][3] = q.w;
    }
    float av[4][4];
#pragma unroll
    for (int ft = 0; ft < 4; ++ft)
#pragma unroll
        for (int r = 0; r < 4; ++r) av[ft][r] = 0.f;
#pragma unroll
    for (int kt = 0; kt < 4; ++kt) {
        float rbm = ((rw >> (kt * 16 + ln)) & 1ull) ? 1.f : 0.f;
#pragma unroll
        for (int ft = 0; ft < 4; ++ft)
#pragma unroll
            for (int r = 0; r < 4; ++r)
                av[ft][r] += rbm * fmaxf(v4r[ft][r] - acc2[ft][kt][r], 0.f);
    }
#pragma unroll
    for (int m = 1; m <= 8; m <<= 1)
#pragma unroll
        for (int ft = 0; ft < 4; ++ft)
#pragma unroll
            for (int r = 0; r < 4; ++r)
                av[ft][r] += __shfl_xor(av[ft][r], m, 64);
    if (ln == 0) {
#pragma unroll
        for (int ft = 0; ft < 4; ++ft) {
            float4 q = make_float4(av[ft][0], av[ft][1], av[ft][2], av[ft][3]);
            *(float4*)&red[w][16 * ft + 4 * grp] = q;
        }
    }
    __syncthreads();
    if (t < F) agg[(size_t)bi * F + t] = red[0][t] + red[1][t] + red[2][t] + red[3][t];
}

// ---------------------------------------------------------------------------
// encode: enc = relu(Unf@X + Unm@agg)   (4 waves split m)
// ---------------------------------------------------------------------------
__global__ __launch_bounds__(256) void encode_kernel(const float* __restrict__ X,
                                                     const float* __restrict__ Unf,
                                                     const float* __restrict__ Unm,
                                                     const float* __restrict__ agg,
                                                     float* __restrict__ enc) {
    int n = blockIdx.x, b = blockIdx.y;
    int t = threadIdx.x, w = t >> 6, f = t & 63;
    __shared__ float red[4][F];
    const float* urow = Unf + (size_t)n * N;
    const float* Xb = X + (size_t)b * N * F;
    float acc = 0.f;
    for (int j = 0; j < 64; ++j) {
        int m = w * 64 + j;
        acc += urow[m] * Xb[m * F + f];
    }
    red[w][f] = acc;
    __syncthreads();
    if (w == 0) {
        float msum = red[0][f] + red[1][f] + red[2][f] + red[3][f];
        float ag = agg[((size_t)b * N + n) * F + f];
        float wrow[F];
        const float4* wr = (const float4*)(Unm + (size_t)f * F);
#pragma unroll
        for (int q = 0; q < 16; ++q) *(float4*)&wrow[q * 4] = wr[q];
        float a = 0.f;
#pragma unroll
        for (int g = 0; g < F; ++g) a = fmaf(wrow[g], __shfl(ag, g, 64), a);
        enc[((size_t)b * N + n) * F + f] = fmaxf(msum + a, 0.f);
    }
}

// ---------------------------------------------------------------------------
// final: out[b,o] = sigmoid(enc_flat[b] . lw[o] + lb[o])   (float4 loads)
// ---------------------------------------------------------------------------
__global__ __launch_bounds__(256) void final_kernel(const float* __restrict__ enc,
                                                    const float* __restrict__ lw,
                                                    const float* __restrict__ lb,
                                                    float* __restrict__ out) {
    int o = blockIdx.x;
    int t = threadIdx.x;
    float acc[B];
#pragma unroll
    for (int b = 0; b < B; ++b) acc[b] = 0.f;
    const float4* lrow = (const float4*)(lw + (size_t)o * (N * F));
    const float4* e4 = (const float4*)enc;
    for (int k = t; k < (N * F) / 4; k += 256) {
        float4 wv = lrow[k];
#pragma unroll
        for (int b = 0; b < B; ++b) {
            float4 ev = e4[b * (N * F / 4) + k];
            acc[b] += wv.x * ev.x + wv.y * ev.y + wv.z * ev.z + wv.w * ev.w;
        }
    }
    __shared__ float red[B][256];
#pragma unroll
    for (int b = 0; b < B; ++b) red[b][t] = acc[b];
    __syncthreads();
    for (int off = 128; off > 0; off >>= 1) {
        if (t < off) {
#pragma unroll
            for (int b = 0; b < B; ++b) red[b][t] += red[b][t + off];
        }
        __syncthreads();
    }
    if (t < B) {
        float z = red[t][0] + lb[o];
        out[t * OUTD + o] = 1.f / (1.f + expf(-z));
    }
}

extern "C" void kernel_launch(void* const* d_in, const int* in_sizes, int n_in,
                              void* d_out, int out_size, void* d_ws, size_t ws_size,
                              hipStream_t stream) {
    const float* X   = (const float*)d_in[0];
    const int*   adj = (const int*)d_in[1];
    const float* Wnf = (const float*)d_in[2];
    const float* Wnm = (const float*)d_in[3];
    const float* Unf = (const float*)d_in[4];
    const float* Unm = (const float*)d_in[5];
    const float* lw  = (const float*)d_in[6];
    const float* lb  = (const float*)d_in[7];
    float* out = (float*)d_out;

    const long BNF = (long)B * N * F;
    u64* rowbits = (u64*)d_ws;
    u64* colbits = rowbits + (long)B * N * 4;
    float* fws = (float*)(colbits + (long)B * N * 4);
    float* base = fws;          fws += BNF;
    float* P    = fws;          fws += BNF;
    float* V2   = fws;          fws += BNF;
    float* V3   = fws;          fws += BNF;
    float* aggp = fws;          fws += BNF;
    float* enc  = fws;          fws += BNF;
    (void)ws_size; (void)in_sizes; (void)n_in; (void)out_size;

    pack_rows_kernel<<<dim3(N / 4, B), 256, 0, stream>>>(adj, rowbits);
    pack_cols_kernel<<<dim3(N / 4, B), 256, 0, stream>>>(rowbits, colbits);
    prep_kernel<<<B * N, F, 0, stream>>>(X, Wnf, Wnm, base, P);
    v2_kernel<<<dim3(N, B), 256, 0, stream>>>(base, P, rowbits, colbits, V2);
    s3_kernel<<<dim3(N, B), 256, 0, stream>>>(base, P, V2, rowbits, colbits, Wnm, V3);
    bigstep_kernel<<<dim3(N, B), 256, 0, stream>>>(base, P, V2, V3, rowbits, colbits, Wnm, aggp);
    encode_kernel<<<dim3(N, B), 256, 0, stream>>>(X, Unf, Unm, aggp, enc);
    final_kernel<<<OUTD, 256, 0, stream>>>(enc, lw, lb, out);
}